// Round 7
// baseline (11846.210 us; speedup 1.0000x reference)
//
#include <hip/hip_runtime.h>

// B=2, T=2048, C=1024, H=16, D=64. Inputs fp32. OUTPUT FP32 (round-7 fix):
// the reference returns float32, and the harness header maps non-bf16 refs
// to float*. r5/r6 bit-identical absmax across wildly different numerics =
// harness was reading my bf16 u16-pairs as fp32 (act[i] ~= bf16(out[2i+1])).
// ROUND 7: r6's scalar diagnostic pipeline UNCHANGED except the final store
// writes fp32 (single-variable experiment; green anchor before optimizing).
//   k1: qkv[m,o] = x[m,:]·W_attn[o,:] + b_attn[o]  -> scatter fp32 [B,H,T,D]
//   k2: in-place RoPE on q,k (one thread owns a (d, d+32) pair)
//   k3: attention row-block: scores -> softmax -> y row (overwrites own q row)
//   k4: out[m,o] = ya[m,:]·W_proj[o,:] + b_proj[o] -> FP32

#define T_SEQ 2048
#define C_EMB 1024
#define NH 16
#define HD 64
#define BT 4096   // B*T

// ---------------- k1: QKV projection (scalar) ----------------
__global__ __launch_bounds__(256) void qkv_simple(const float* __restrict__ x,
                                                  const float* __restrict__ Wa,
                                                  const float* __restrict__ ba,
                                                  float* __restrict__ q, float* __restrict__ k,
                                                  float* __restrict__ v) {
    int idx = blockIdx.x * 256 + threadIdx.x;       // 4096*3072
    int m = idx / 3072;                              // row in B*T
    int o = idx - m * 3072;                          // 0..3071
    float acc = 0.f;
    const float* xr = x + (size_t)m * C_EMB;
    const float* wr = Wa + (size_t)o * C_EMB;
    for (int c = 0; c < C_EMB; ++c) acc = fmaf(xr[c], wr[c], acc);
    acc += ba[o];
    int sec = o >> 10;                               // 0=q 1=k 2=v
    int oo = o & 1023;
    int h = oo >> 6, d = oo & 63;
    int b = m >> 11, t = m & 2047;
    float* dst = sec == 0 ? q : (sec == 1 ? k : v);
    dst[(((size_t)(b * NH + h)) * T_SEQ + t) * HD + d] = acc;
}

// ---------------- k2: RoPE in place (pairs) ----------------
__global__ __launch_bounds__(256) void rope_simple(float* __restrict__ q, float* __restrict__ k) {
    int idx = blockIdx.x * 256 + threadIdx.x;        // idx = ((which*65536)+bht)*32 + p
    int p = idx & 31;
    int which = idx >> 21;                           // 65536 = 2*16*2048 rows per tensor
    int bht = (idx >> 5) & 65535;
    float* buf = which == 0 ? q : k;
    size_t base = (size_t)bht * HD;
    float inv = __builtin_exp2f(-0.41524101186092f * (float)p);  // 10000^(-p/32)
    int t = bht & 2047;                              // bht = (b*16+h)*2048 + t
    float s_, c_;
    sincosf((float)t * inv, &s_, &c_);
    float a = buf[base + p];
    float bq = buf[base + p + 32];
    buf[base + p]      = a * c_ - bq * s_;
    buf[base + p + 32] = bq * c_ + a * s_;
}

// ---------------- k3: attention, one block per (bh, qi) row ----------------
__global__ __launch_bounds__(256) void attn_simple(float* __restrict__ q, const float* __restrict__ k,
                                                   const float* __restrict__ v) {
    int qi = blockIdx.x;                             // 0..2047
    int bh = blockIdx.y;                             // 0..31
    float* qh = q + (size_t)bh * T_SEQ * HD;
    const float* kh = k + (size_t)bh * T_SEQ * HD;
    const float* vh = v + (size_t)bh * T_SEQ * HD;
    __shared__ float qrow[64];
    __shared__ float s[T_SEQ];
    __shared__ float red[256];
    __shared__ float mval, lval;
    int tid = threadIdx.x;
    if (tid < 64) qrow[tid] = qh[(size_t)qi * HD + tid] * 0.125f;
    __syncthreads();
    float pm = -1e30f;
    for (int j = tid; j <= qi; j += 256) {
        float acc = 0.f;
        const float* kr = kh + (size_t)j * HD;
        for (int d = 0; d < 64; ++d) acc = fmaf(qrow[d], kr[d], acc);
        s[j] = acc;
        pm = fmaxf(pm, acc);
    }
    red[tid] = pm;
    __syncthreads();
    if (tid == 0) {
        float m = -1e30f;
        for (int i = 0; i < 256; ++i) m = fmaxf(m, red[i]);
        mval = m;
    }
    __syncthreads();
    float ps = 0.f;
    for (int j = tid; j <= qi; j += 256) {
        float e = __expf(s[j] - mval);
        s[j] = e;
        ps += e;
    }
    red[tid] = ps;
    __syncthreads();
    if (tid == 0) {
        float l = 0.f;
        for (int i = 0; i < 256; ++i) l += red[i];
        lval = l;
    }
    __syncthreads();
    if (tid < 64) {
        float acc = 0.f;
        for (int j = 0; j <= qi; ++j) acc = fmaf(s[j], vh[(size_t)j * HD + tid], acc);
        // overwrite own q row with y (no other block touches this row)
        qh[(size_t)qi * HD + tid] = acc / lval;
    }
}

// ---------------- k4: output projection (scalar, fp32 out) ----------------
// ya lives in q with [B,H,T,D] layout.
__global__ __launch_bounds__(256) void proj_simple(const float* __restrict__ ya,
                                                   const float* __restrict__ Wp,
                                                   const float* __restrict__ bp,
                                                   float* __restrict__ out) {
    int idx = blockIdx.x * 256 + threadIdx.x;        // 4096*1024
    int m = idx >> 10;
    int o = idx & 1023;
    int b = m >> 11, t = m & 2047;
    float acc = 0.f;
    const float* wr = Wp + (size_t)o * C_EMB;
    for (int c = 0; c < C_EMB; ++c) {
        int h = c >> 6, d = c & 63;
        float yv = ya[(((size_t)(b * NH + h)) * T_SEQ + t) * HD + d];
        acc = fmaf(yv, wr[c], acc);
    }
    acc += bp[o];
    out[(size_t)m * C_EMB + o] = acc;                // FP32 store (the fix)
}

extern "C" void kernel_launch(void* const* d_in, const int* in_sizes, int n_in,
                              void* d_out, int out_size, void* d_ws, size_t ws_size,
                              hipStream_t stream) {
    // Inputs resolved BY ELEMENT COUNT (unique): x 4194304, W_attn 3145728,
    // b_attn 3072, W_proj 1048576, b_proj 1024. All fp32.
    const float *x = nullptr, *Wa = nullptr, *ba = nullptr, *Wp = nullptr, *bp = nullptr;
    for (int i = 0; i < n_in; ++i) {
        switch (in_sizes[i]) {
            case 4194304: x  = (const float*)d_in[i]; break;
            case 3145728: Wa = (const float*)d_in[i]; break;
            case 3072:    ba = (const float*)d_in[i]; break;
            case 1048576: Wp = (const float*)d_in[i]; break;
            case 1024:    bp = (const float*)d_in[i]; break;
            default: break;
        }
    }
    float* out = (float*)d_out;

    char* ws = (char*)d_ws;
    float* q = (float*)(ws);                  //  0..16 MiB (later holds ya)
    float* k = (float*)(ws + 16777216);       // 16..32 MiB
    float* v = (float*)(ws + 33554432);       // 32..48 MiB

    qkv_simple<<<49152, 256, 0, stream>>>(x, Wa, ba, q, k, v);
    rope_simple<<<16384, 256, 0, stream>>>(q, k);    // 2*65536*32 threads
    attn_simple<<<dim3(2048, 32), 256, 0, stream>>>(q, k, v);
    proj_simple<<<16384, 256, 0, stream>>>(q, Wp, bp, out);
}

// Round 8
// 1260.011 us; speedup vs baseline: 9.4017x; 9.4017x over previous
//
#include <hip/hip_runtime.h>

// B=2, T=2048, C=1024, H=16, D=64. Inputs fp32, OUTPUT fp32 (r7 green anchor:
// absmax 0.00195 @ 11846 us scalar). Round 8: tiled LDS pipeline (validated
// numerics from r2-r5), fp32 end-to-end, fp32 output store.
//   k1: qkv = x @ W_attn^T + b ; rope(q,k) ; scatter q,k,v fp32 [B,H,T,D]
//   k2: flash attention (64x64 tiles, online softmax, causal) -> ya into q buf
//   k3: out = ya @ W_proj^T + b_proj -> fp32

typedef float f32x4 __attribute__((ext_vector_type(4)));

#define T_SEQ 2048
#define C_EMB 1024
#define NH 16
#define HD 64
#define BT 4096   // B*T

// Stage a 64x64 fp32 tile at (r0,c0) of row-major g (ld) into dst[k][m]
// (transposed). 256 threads, float4 coalesced loads.
__device__ __forceinline__ void stage_f32_T(float (*dst)[68], const float* __restrict__ g,
                                            int r0, int c0, int ld, int tid, float scale) {
#pragma unroll
    for (int it = 0; it < 4; ++it) {
        int c = tid + it * 256;
        int row = c >> 4, koff = (c & 15) << 2;
        f32x4 u = *(const f32x4*)(g + (size_t)(r0 + row) * ld + c0 + koff);
#pragma unroll
        for (int jj = 0; jj < 4; ++jj) dst[koff + jj][row] = u[jj] * scale;
    }
}

// ---------------- k1: QKV + bias + RoPE ----------------
__global__ __launch_bounds__(256) void qkv_rope_k(const float* __restrict__ x, const float* __restrict__ W,
                                                  const float* __restrict__ bias,
                                                  float* __restrict__ qb, float* __restrict__ kb,
                                                  float* __restrict__ vb) {
    __shared__ float As[64][68];   // [k][m] x tile
    __shared__ float Bs[64][68];   // [k][n] W tile
    int tid = threadIdx.x;
    int n0 = blockIdx.x * 64;      // output col (0..3071)
    int m0 = blockIdx.y * 64;      // row in B*T
    int ti = tid >> 4, tj = tid & 15;
    float acc[4][4] = {};
    for (int kt = 0; kt < C_EMB; kt += 64) {
        stage_f32_T(As, x, m0, kt, C_EMB, tid, 1.0f);
        stage_f32_T(Bs, W, n0, kt, C_EMB, tid, 1.0f);
        __syncthreads();
#pragma unroll
        for (int kk = 0; kk < 64; ++kk) {
            f32x4 a = *(const f32x4*)&As[kk][ti * 4];
            f32x4 b = *(const f32x4*)&Bs[kk][tj * 4];
#pragma unroll
            for (int r = 0; r < 4; ++r)
#pragma unroll
                for (int c = 0; c < 4; ++c) acc[r][c] = fmaf(a[r], b[c], acc[r][c]);
        }
        __syncthreads();
    }
    float (*Cs)[68] = As;
#pragma unroll
    for (int r = 0; r < 4; ++r)
#pragma unroll
        for (int c = 0; c < 4; ++c)
            Cs[ti * 4 + r][tj * 4 + c] = acc[r][c] + bias[n0 + tj * 4 + c];
    __syncthreads();

    int sec = n0 >> 10;            // 0=q 1=k 2=v
    int h = (n0 & 1023) >> 6;      // head (tile width 64 == head dim)
    int row = tid >> 2;            // token row within tile
    int d0 = (tid & 3) << 4;       // 16-wide d slice
    int m = m0 + row;
    int b = m >> 11;               // /2048
    int tpos = m & 2047;
    size_t base = (((size_t)(b * NH + h)) * T_SEQ + tpos) * HD + d0;
    float res[16];
    if (sec == 2) {
#pragma unroll
        for (int dd = 0; dd < 16; ++dd) res[dd] = Cs[row][d0 + dd];
    } else {
        float tf = (float)tpos;
#pragma unroll
        for (int dd = 0; dd < 16; ++dd) {
            int d = d0 + dd;
            int j = d & 31;
            float inv = __builtin_exp2f(-0.41524101186092f * (float)j);  // 10000^(-j/32)
            float s_, c_;
            sincosf(tf * inv, &s_, &c_);
            float val = Cs[row][d];
            float rot = (d < 32) ? -Cs[row][d + 32] : Cs[row][d - 32];
            res[dd] = fmaf(val, c_, rot * s_);
        }
    }
    float* dst = (sec == 0) ? qb : (sec == 1 ? kb : vb);
#pragma unroll
    for (int p = 0; p < 4; ++p)
        *(f32x4*)(dst + base + p * 4) = *(f32x4*)&res[p * 4];
}

// ---------------- k2: flash attention ----------------
__global__ __launch_bounds__(256) void flash_k(float* __restrict__ qb, const float* __restrict__ kb,
                                               const float* __restrict__ vb) {
    __shared__ float Qs[64][68];   // [d][i], pre-scaled by 1/8
    __shared__ float Ks[64][68];   // [d][j]
    __shared__ float Vs[64][68];   // [j][d]
    __shared__ float Ss[64][65];   // scores -> probs
    __shared__ float rowm[64], rowl[64], alf[64];
    int tid = threadIdx.x;
    int qt = blockIdx.x;           // 0..31 q tile
    int bh = blockIdx.y;           // 0..31 (b*16+h)
    float* qh = qb + (size_t)bh * T_SEQ * HD;
    const float* kh = kb + (size_t)bh * T_SEQ * HD;
    const float* vh = vb + (size_t)bh * T_SEQ * HD;
    int q0 = qt * 64;
    stage_f32_T(Qs, qh, q0, 0, HD, tid, 0.125f);
    if (tid < 64) { rowm[tid] = -1e30f; rowl[tid] = 0.f; }
    int ti = tid >> 4, tj = tid & 15;
    int io = tid >> 2, d0 = (tid & 3) << 4;
    float oacc[16];
#pragma unroll
    for (int dd = 0; dd < 16; ++dd) oacc[dd] = 0.f;

    for (int kt = 0; kt <= qt; ++kt) {
        int k0 = kt * 64;
        stage_f32_T(Ks, kh, k0, 0, HD, tid, 1.0f);
        // stage V (non-transposed [j][d])
#pragma unroll
        for (int it = 0; it < 4; ++it) {
            int c = tid + it * 256;
            int row = c >> 4, doff = (c & 15) << 2;
            *(f32x4*)&Vs[row][doff] = *(const f32x4*)(vh + (size_t)(k0 + row) * HD + doff);
        }
        __syncthreads();
        // S = (Q/8) K^T, 4x4 per thread
        float sacc[4][4] = {};
#pragma unroll
        for (int d = 0; d < 64; ++d) {
            f32x4 a = *(const f32x4*)&Qs[d][ti * 4];
            f32x4 b = *(const f32x4*)&Ks[d][tj * 4];
#pragma unroll
            for (int r = 0; r < 4; ++r)
#pragma unroll
                for (int c = 0; c < 4; ++c) sacc[r][c] = fmaf(a[r], b[c], sacc[r][c]);
        }
        if (kt == qt) {
#pragma unroll
            for (int r = 0; r < 4; ++r)
#pragma unroll
                for (int c = 0; c < 4; ++c)
                    if (tj * 4 + c > ti * 4 + r) sacc[r][c] = -1e30f;
        }
#pragma unroll
        for (int r = 0; r < 4; ++r)
#pragma unroll
            for (int c = 0; c < 4; ++c) Ss[ti * 4 + r][tj * 4 + c] = sacc[r][c];
        __syncthreads();
        // online softmax, one thread per row
        if (tid < 64) {
            int i = tid;
            float mo = rowm[i], mx = mo;
            for (int j = 0; j < 64; ++j) mx = fmaxf(mx, Ss[i][j]);
            float a = __expf(mo - mx);
            float sum = 0.f;
            for (int j = 0; j < 64; ++j) { float p = __expf(Ss[i][j] - mx); Ss[i][j] = p; sum += p; }
            rowl[i] = rowl[i] * a + sum;
            rowm[i] = mx;
            alf[i] = a;
        }
        __syncthreads();
        // O = alpha*O + P @ V
        float a = alf[io];
#pragma unroll
        for (int dd = 0; dd < 16; ++dd) oacc[dd] *= a;
        for (int j = 0; j < 64; ++j) {
            float p = Ss[io][j];
            f32x4 v0 = *(const f32x4*)&Vs[j][d0];
            f32x4 v1 = *(const f32x4*)&Vs[j][d0 + 4];
            f32x4 v2 = *(const f32x4*)&Vs[j][d0 + 8];
            f32x4 v3 = *(const f32x4*)&Vs[j][d0 + 12];
#pragma unroll
            for (int dd = 0; dd < 4; ++dd) {
                oacc[dd]      = fmaf(p, v0[dd], oacc[dd]);
                oacc[4 + dd]  = fmaf(p, v1[dd], oacc[4 + dd]);
                oacc[8 + dd]  = fmaf(p, v2[dd], oacc[8 + dd]);
                oacc[12 + dd] = fmaf(p, v3[dd], oacc[12 + dd]);
            }
        }
        __syncthreads();
    }
    // write O tile into the q buffer slot (ya in [B,H,T,D] layout); this
    // block is the only reader of its q tile and has consumed it.
    float inv = 1.f / rowl[io];
    size_t base = (size_t)(q0 + io) * HD + d0;
#pragma unroll
    for (int p = 0; p < 4; ++p) {
        f32x4 o;
#pragma unroll
        for (int dd = 0; dd < 4; ++dd) o[dd] = oacc[p * 4 + dd] * inv;
        *(f32x4*)(qh + base + p * 4) = o;
    }
}

// ---------------- k3: output projection ----------------
// ya lives in qb with [B,H,T,D] layout: ya[b,t,h*64+d] = qb[((b*16+h)*2048+t)*64+d]
__global__ __launch_bounds__(256) void proj_k(const float* __restrict__ yaq, const float* __restrict__ W,
                                              const float* __restrict__ bias, float* __restrict__ out) {
    __shared__ float As[64][68];
    __shared__ float Bs[64][68];
    int tid = threadIdx.x;
    int n0 = blockIdx.x * 64;
    int m0 = blockIdx.y * 64;
    int ti = tid >> 4, tj = tid & 15;
    float acc[4][4] = {};
    for (int kt = 0; kt < C_EMB; kt += 64) {
        int h = kt >> 6;
#pragma unroll
        for (int it = 0; it < 4; ++it) {
            int c = tid + it * 256;
            int row = c >> 4, koff = (c & 15) << 2;
            int m = m0 + row;
            int b = m >> 11, tpos = m & 2047;
            f32x4 u = *(const f32x4*)(yaq + (((size_t)(b * NH + h)) * T_SEQ + tpos) * HD + koff);
#pragma unroll
            for (int jj = 0; jj < 4; ++jj) As[koff + jj][row] = u[jj];
        }
        stage_f32_T(Bs, W, n0, kt, C_EMB, tid, 1.0f);
        __syncthreads();
#pragma unroll
        for (int kk = 0; kk < 64; ++kk) {
            f32x4 a = *(const f32x4*)&As[kk][ti * 4];
            f32x4 b = *(const f32x4*)&Bs[kk][tj * 4];
#pragma unroll
            for (int r = 0; r < 4; ++r)
#pragma unroll
                for (int c = 0; c < 4; ++c) acc[r][c] = fmaf(a[r], b[c], acc[r][c]);
        }
        __syncthreads();
    }
    float (*Cs)[68] = As;
#pragma unroll
    for (int r = 0; r < 4; ++r)
#pragma unroll
        for (int c = 0; c < 4; ++c)
            Cs[ti * 4 + r][tj * 4 + c] = acc[r][c] + bias[n0 + tj * 4 + c];
    __syncthreads();
    int row = tid >> 2;
    int d0 = (tid & 3) << 4;
    size_t base = (size_t)(m0 + row) * C_EMB + n0 + d0;
#pragma unroll
    for (int p = 0; p < 4; ++p)
        *(f32x4*)(out + base + p * 4) = *(const f32x4*)&Cs[row][d0 + p * 4];
}

extern "C" void kernel_launch(void* const* d_in, const int* in_sizes, int n_in,
                              void* d_out, int out_size, void* d_ws, size_t ws_size,
                              hipStream_t stream) {
    // Inputs resolved BY ELEMENT COUNT (unique): x 4194304, W_attn 3145728,
    // b_attn 3072, W_proj 1048576, b_proj 1024. All fp32.
    const float *x = nullptr, *Wa = nullptr, *ba = nullptr, *Wp = nullptr, *bp = nullptr;
    for (int i = 0; i < n_in; ++i) {
        switch (in_sizes[i]) {
            case 4194304: x  = (const float*)d_in[i]; break;
            case 3145728: Wa = (const float*)d_in[i]; break;
            case 3072:    ba = (const float*)d_in[i]; break;
            case 1048576: Wp = (const float*)d_in[i]; break;
            case 1024:    bp = (const float*)d_in[i]; break;
            default: break;
        }
    }
    float* out = (float*)d_out;

    char* ws = (char*)d_ws;
    float* qb = (float*)(ws);                  //  0..16 MiB (later holds ya)
    float* kb = (float*)(ws + 16777216);       // 16..32 MiB
    float* vb = (float*)(ws + 33554432);       // 32..48 MiB

    qkv_rope_k<<<dim3(48, 64), 256, 0, stream>>>(x, Wa, ba, qb, kb, vb);
    flash_k<<<dim3(32, 32), 256, 0, stream>>>(qb, kb, vb);
    proj_k<<<dim3(16, 64), 256, 0, stream>>>(qb, Wp, bp, out);
}

// Round 9
// 397.641 us; speedup vs baseline: 29.7912x; 3.1687x over previous
//
#include <hip/hip_runtime.h>

// B=2, T=2048, C=1024, H=16, D=64. Inputs fp32, OUTPUT fp32.
// Round 9: MFMA everywhere (v_mfma_f32_16x16x32_bf16, verified layouts:
//   A: m=lane&15, k=quad*8+j | B: k=quad*8+j, n=lane&15 | C/D: col=lane&15,
//   row=quad*4+reg).
// k1: qkv GEMM 128x128 tiles + in-register RoPE epilogue; q(*0.125),k bf16
//     [B,H,T,D]; V stored TRANSPOSED bf16 [B,H,D,T] (makes PV b-frags
//     k-contiguous in flash).
// k2: flash attention, barrier-free: per-wave 16-row Q strip, Q/K/Vt frags
//     direct from global, online softmax via shfl_xor over 16-lane quads,
//     P through per-wave LDS (C->A layout round-trip). ya bf16 [B,T,C].
// k3: proj GEMM 128x128 tiles -> fp32 out.

typedef unsigned short u16;
typedef u16 u16x4 __attribute__((ext_vector_type(4)));
typedef short s16x8 __attribute__((ext_vector_type(8)));
typedef float f32x4 __attribute__((ext_vector_type(4)));

#define T_SEQ 2048
#define C_EMB 1024
#define NH 16
#define HD 64

#define MFMA16(a, b, c) __builtin_amdgcn_mfma_f32_16x16x32_bf16(a, b, c, 0, 0, 0)

__device__ __forceinline__ u16 f2bf(float f) {
    union { float f; unsigned int i; } x; x.f = f;
    unsigned int r = x.i + 0x7fffu + ((x.i >> 16) & 1u);
    return (u16)(r >> 16);
}
__device__ __forceinline__ u16x4 pack4(f32x4 v) {
    u16x4 o;
#pragma unroll
    for (int j = 0; j < 4; ++j) o[j] = f2bf(v[j]);
    return o;
}

// ---------------- k1: QKV GEMM + RoPE (MFMA) ----------------
// grid (24, 32): n0 = bx*128 (0..3071), m0 = by*128 (0..4095)
__global__ __launch_bounds__(256) void qkv_rope_k(const float* __restrict__ x, const float* __restrict__ W,
                                                  const float* __restrict__ bias,
                                                  u16* __restrict__ qb, u16* __restrict__ kb,
                                                  u16* __restrict__ vt) {
    __shared__ u16 As[128 * 72];
    __shared__ u16 Bs[128 * 72];
    int tid = threadIdx.x;
    int n0 = blockIdx.x * 128, m0 = blockIdx.y * 128;
    int w = tid >> 6, lane = tid & 63, lr = lane & 15, quad = lane >> 4;
    int wr = w >> 1, wc = w & 1;
    f32x4 acc[4][4] = {};
    for (int kt = 0; kt < C_EMB; kt += 64) {
#pragma unroll
        for (int it = 0; it < 8; ++it) {
            int idx = it * 256 + tid;
            int row = idx >> 4, k4 = (idx & 15) << 2;
            f32x4 a = *(const f32x4*)(x + (size_t)(m0 + row) * C_EMB + kt + k4);
            f32x4 b = *(const f32x4*)(W + (size_t)(n0 + row) * C_EMB + kt + k4);
            *(u16x4*)&As[row * 72 + k4] = pack4(a);
            *(u16x4*)&Bs[row * 72 + k4] = pack4(b);
        }
        __syncthreads();
#pragma unroll
        for (int ks = 0; ks < 64; ks += 32) {
            s16x8 af[4], bf[4];
#pragma unroll
            for (int i = 0; i < 4; ++i)
                af[i] = *(const s16x8*)&As[(wr * 64 + i * 16 + lr) * 72 + ks + quad * 8];
#pragma unroll
            for (int j = 0; j < 4; ++j)
                bf[j] = *(const s16x8*)&Bs[(wc * 64 + j * 16 + lr) * 72 + ks + quad * 8];
#pragma unroll
            for (int i = 0; i < 4; ++i)
#pragma unroll
                for (int j = 0; j < 4; ++j) acc[i][j] = MFMA16(af[i], bf[j], acc[i][j]);
        }
        __syncthreads();
    }
    int sec = n0 >> 10;                       // 0=q 1=k 2=v (blocks never straddle)
    int h = ((n0 & 1023) >> 6) + wc;          // head for this wave-column
    float bv[4];
#pragma unroll
    for (int j = 0; j < 4; ++j) bv[j] = bias[n0 + wc * 64 + j * 16 + lr];

    if (sec == 2) {
        // V transposed store: vt[((b*16+h)*64 + d)*2048 + t]
#pragma unroll
        for (int i = 0; i < 4; ++i)
#pragma unroll
            for (int r = 0; r < 4; ++r) {
                int m = m0 + wr * 64 + i * 16 + quad * 4 + r;
                int b = m >> 11, t = m & 2047;
                size_t hb = (size_t)(b * NH + h) * HD;
#pragma unroll
                for (int j = 0; j < 4; ++j) {
                    int d = j * 16 + lr;
                    vt[(hb + d) * T_SEQ + t] = f2bf(acc[i][j][r] + bv[j]);
                }
            }
    } else {
        u16* dst = (sec == 0) ? qb : kb;
        float qs = (sec == 0) ? 0.125f : 1.0f;   // fold 1/sqrt(D) into q
#pragma unroll
        for (int i = 0; i < 4; ++i)
#pragma unroll
            for (int r = 0; r < 4; ++r) {
                int m = m0 + wr * 64 + i * 16 + quad * 4 + r;
                int b = m >> 11, t = m & 2047;
                size_t base = ((size_t)(b * NH + h) * T_SEQ + t) * HD;
                float tf = (float)t;
#pragma unroll
                for (int j = 0; j < 2; ++j) {
                    int d1 = j * 16 + lr;                 // 0..31; partner d1+32 in tile j+2
                    float inv = __builtin_exp2f(-0.41524101186092f * (float)d1);
                    float s_, c_;
                    sincosf(tf * inv, &s_, &c_);
                    float v1 = acc[i][j][r] + bv[j];
                    float v2 = acc[i][j + 2][r] + bv[j + 2];
                    dst[base + d1]      = f2bf((v1 * c_ - v2 * s_) * qs);
                    dst[base + d1 + 32] = f2bf((v2 * c_ + v1 * s_) * qs);
                }
            }
    }
}

// ---------------- k2: flash attention (MFMA, barrier-free) ----------------
// grid (32, 32): q-tile, bh. 4 waves; wave w owns Q rows q0+w*16..+15.
__global__ __launch_bounds__(256) void flash_k(const u16* __restrict__ qb, const u16* __restrict__ kb,
                                               const u16* __restrict__ vt, u16* __restrict__ yab) {
    __shared__ u16 Ps[4][16 * 72];           // per-wave P strip (C->A round-trip)
    int tid = threadIdx.x;
    int bx = blockIdx.x;
    int qt = (bx & 1) ? (31 - (bx >> 1)) : (bx >> 1);   // balance: pair (0,31),(1,30)...
    int bh = blockIdx.y;
    int w = tid >> 6, lane = tid & 63, lr = lane & 15, quad = lane >> 4;
    int q0 = qt * 64;
    const u16* qh = qb + (size_t)bh * T_SEQ * HD;
    const u16* kh = kb + (size_t)bh * T_SEQ * HD;
    const u16* vh = vt + (size_t)bh * HD * T_SEQ;

    s16x8 aq[2];
#pragma unroll
    for (int ks = 0; ks < 2; ++ks)
        aq[ks] = *(const s16x8*)(qh + (size_t)(q0 + w * 16 + lr) * HD + ks * 32 + quad * 8);

    float m_i[4], l_i[4];
#pragma unroll
    for (int r = 0; r < 4; ++r) { m_i[r] = -1e30f; l_i[r] = 0.f; }
    f32x4 oacc[4] = {};

    for (int kt = 0; kt <= qt; ++kt) {
        int k0 = kt * 64;
        f32x4 sacc[4] = {};
#pragma unroll
        for (int ks = 0; ks < 2; ++ks)
#pragma unroll
            for (int tc = 0; tc < 4; ++tc) {
                s16x8 bk = *(const s16x8*)(kh + (size_t)(k0 + tc * 16 + lr) * HD + ks * 32 + quad * 8);
                sacc[tc] = MFMA16(aq[ks], bk, sacc[tc]);
            }
        if (kt == qt) {
#pragma unroll
            for (int tc = 0; tc < 4; ++tc)
#pragma unroll
                for (int r = 0; r < 4; ++r)
                    if (tc * 16 + lr > w * 16 + quad * 4 + r) sacc[tc][r] = -1e30f;
        }
        float alpha[4];
#pragma unroll
        for (int r = 0; r < 4; ++r) {
            float mx = fmaxf(fmaxf(sacc[0][r], sacc[1][r]), fmaxf(sacc[2][r], sacc[3][r]));
#pragma unroll
            for (int off = 1; off < 16; off <<= 1) mx = fmaxf(mx, __shfl_xor(mx, off, 64));
            float mn = fmaxf(m_i[r], mx);
            alpha[r] = __expf(m_i[r] - mn);
            m_i[r] = mn;
            float rs = 0.f;
#pragma unroll
            for (int tc = 0; tc < 4; ++tc) {
                float p = __expf(sacc[tc][r] - mn);
                sacc[tc][r] = p;
                rs += p;
            }
#pragma unroll
            for (int off = 1; off < 16; off <<= 1) rs += __shfl_xor(rs, off, 64);
            l_i[r] = l_i[r] * alpha[r] + rs;
        }
        // P (C-layout) -> LDS -> A-layout; rescale O meanwhile
#pragma unroll
        for (int tc = 0; tc < 4; ++tc)
#pragma unroll
            for (int r = 0; r < 4; ++r)
                Ps[w][(quad * 4 + r) * 72 + tc * 16 + lr] = f2bf(sacc[tc][r]);
#pragma unroll
        for (int tn = 0; tn < 4; ++tn)
#pragma unroll
            for (int r = 0; r < 4; ++r) oacc[tn][r] *= alpha[r];
#pragma unroll
        for (int ks = 0; ks < 2; ++ks) {
            s16x8 ap = *(const s16x8*)&Ps[w][lr * 72 + ks * 32 + quad * 8];
#pragma unroll
            for (int tn = 0; tn < 4; ++tn) {
                s16x8 bv = *(const s16x8*)(vh + (size_t)(tn * 16 + lr) * T_SEQ + k0 + ks * 32 + quad * 8);
                oacc[tn] = MFMA16(ap, bv, oacc[tn]);
            }
        }
    }
    int b = bh >> 4, hh = bh & 15;
#pragma unroll
    for (int r = 0; r < 4; ++r) {
        float inv = 1.f / l_i[r];
        int t = q0 + w * 16 + quad * 4 + r;
        size_t base = ((size_t)b * T_SEQ + t) * C_EMB + hh * HD;
#pragma unroll
        for (int tn = 0; tn < 4; ++tn)
            yab[base + tn * 16 + lr] = f2bf(oacc[tn][r] * inv);
    }
}

// ---------------- k3: output projection (MFMA) ----------------
// grid (8, 32): n0 = bx*128 (0..1023), m0 = by*128
__global__ __launch_bounds__(256) void proj_k(const u16* __restrict__ ya, const float* __restrict__ W,
                                              const float* __restrict__ bias, float* __restrict__ out) {
    __shared__ u16 As[128 * 72];
    __shared__ u16 Bs[128 * 72];
    int tid = threadIdx.x;
    int n0 = blockIdx.x * 128, m0 = blockIdx.y * 128;
    int w = tid >> 6, lane = tid & 63, lr = lane & 15, quad = lane >> 4;
    int wr = w >> 1, wc = w & 1;
    f32x4 acc[4][4] = {};
    for (int kt = 0; kt < C_EMB; kt += 64) {
#pragma unroll
        for (int it = 0; it < 8; ++it) {
            int idx = it * 256 + tid;
            int row = idx >> 4, k4 = (idx & 15) << 2;
            *(u16x4*)&As[row * 72 + k4] = *(const u16x4*)(ya + (size_t)(m0 + row) * C_EMB + kt + k4);
            f32x4 b = *(const f32x4*)(W + (size_t)(n0 + row) * C_EMB + kt + k4);
            *(u16x4*)&Bs[row * 72 + k4] = pack4(b);
        }
        __syncthreads();
#pragma unroll
        for (int ks = 0; ks < 64; ks += 32) {
            s16x8 af[4], bf[4];
#pragma unroll
            for (int i = 0; i < 4; ++i)
                af[i] = *(const s16x8*)&As[(wr * 64 + i * 16 + lr) * 72 + ks + quad * 8];
#pragma unroll
            for (int j = 0; j < 4; ++j)
                bf[j] = *(const s16x8*)&Bs[(wc * 64 + j * 16 + lr) * 72 + ks + quad * 8];
#pragma unroll
            for (int i = 0; i < 4; ++i)
#pragma unroll
                for (int j = 0; j < 4; ++j) acc[i][j] = MFMA16(af[i], bf[j], acc[i][j]);
        }
        __syncthreads();
    }
    float bv[4];
#pragma unroll
    for (int j = 0; j < 4; ++j) bv[j] = bias[n0 + wc * 64 + j * 16 + lr];
#pragma unroll
    for (int i = 0; i < 4; ++i)
#pragma unroll
        for (int r = 0; r < 4; ++r) {
            int m = m0 + wr * 64 + i * 16 + quad * 4 + r;
#pragma unroll
            for (int j = 0; j < 4; ++j)
                out[(size_t)m * C_EMB + n0 + wc * 64 + j * 16 + lr] = acc[i][j][r] + bv[j];
        }
}

extern "C" void kernel_launch(void* const* d_in, const int* in_sizes, int n_in,
                              void* d_out, int out_size, void* d_ws, size_t ws_size,
                              hipStream_t stream) {
    // Inputs resolved BY ELEMENT COUNT (unique): x 4194304, W_attn 3145728,
    // b_attn 3072, W_proj 1048576, b_proj 1024. All fp32.
    const float *x = nullptr, *Wa = nullptr, *ba = nullptr, *Wp = nullptr, *bp = nullptr;
    for (int i = 0; i < n_in; ++i) {
        switch (in_sizes[i]) {
            case 4194304: x  = (const float*)d_in[i]; break;
            case 3145728: Wa = (const float*)d_in[i]; break;
            case 3072:    ba = (const float*)d_in[i]; break;
            case 1048576: Wp = (const float*)d_in[i]; break;
            case 1024:    bp = (const float*)d_in[i]; break;
            default: break;
        }
    }
    float* out = (float*)d_out;

    char* ws = (char*)d_ws;
    u16* qb  = (u16*)(ws);                    //  0.. 8 MiB  bf16 [B,H,T,D] (q*0.125)
    u16* kb  = (u16*)(ws + 8388608);          //  8..16 MiB  bf16 [B,H,T,D]
    u16* vt  = (u16*)(ws + 16777216);         // 16..24 MiB  bf16 [B,H,D,T]
    u16* yab = (u16*)(ws + 25165824);         // 24..32 MiB  bf16 [B,T,C]

    qkv_rope_k<<<dim3(24, 32), 256, 0, stream>>>(x, Wa, ba, qb, kb, vt);
    flash_k<<<dim3(32, 32), 256, 0, stream>>>(qb, kb, vt, yab);
    proj_k<<<dim3(8, 32), 256, 0, stream>>>(yab, Wp, bp, out);
}

// Round 10
// 320.455 us; speedup vs baseline: 36.9669x; 1.2409x over previous
//
#include <hip/hip_runtime.h>

// B=2, T=2048, C=1024, H=16, D=64. Inputs fp32, OUTPUT fp32.
// Round 10: flash restructure + k1 epilogue fixes.
//   k0: rope cos/sin float2 table [T][32] (replaces 32 sincosf/thread in k1)
//   k1: qkv GEMM 128x128 MFMA + rope-table epilogue; q(*0.125),k bf16
//       [B,H,T,D]; V transposed to [B,H,D,T] via LDS (coalesced 16B stores).
//   k2: flash: 128-row Q tile, 4 waves x 2 strips; K/V tiles staged in LDS
//       cooperatively; online softmax via 16-lane shfl; P via per-wave LDS.
//   k3: proj GEMM 128x128 MFMA -> fp32.
// MFMA 16x16x32_bf16 layouts (HW-verified): A: m=lane&15,k=quad*8+j;
// B: k=quad*8+j,n=lane&15; C/D: col=lane&15,row=quad*4+reg.

typedef unsigned short u16;
typedef u16 u16x4 __attribute__((ext_vector_type(4)));
typedef short s16x8 __attribute__((ext_vector_type(8)));
typedef float f32x4 __attribute__((ext_vector_type(4)));

#define T_SEQ 2048
#define C_EMB 1024
#define NH 16
#define HD 64

#define MFMA16(a, b, c) __builtin_amdgcn_mfma_f32_16x16x32_bf16(a, b, c, 0, 0, 0)

__device__ __forceinline__ u16 f2bf(float f) {
    union { float f; unsigned int i; } x; x.f = f;
    unsigned int r = x.i + 0x7fffu + ((x.i >> 16) & 1u);
    return (u16)(r >> 16);
}
__device__ __forceinline__ u16x4 pack4(f32x4 v) {
    u16x4 o;
#pragma unroll
    for (int j = 0; j < 4; ++j) o[j] = f2bf(v[j]);
    return o;
}

// ---------------- k0: rope tables ----------------
__global__ __launch_bounds__(256) void rope_tab_k(float2* __restrict__ tab) {
    int idx = blockIdx.x * 256 + threadIdx.x;   // 65536 = T*32
    int t = idx >> 5, j = idx & 31;
    float inv = __builtin_exp2f(-0.41524101186092f * (float)j);  // 10000^(-j/32)
    float s_, c_;
    sincosf((float)t * inv, &s_, &c_);
    tab[idx] = make_float2(c_, s_);
}

// ---------------- k1: QKV GEMM + RoPE (MFMA) ----------------
// grid (24, 32): n0 = bx*128 (0..3071), m0 = by*128 (0..4095)
__global__ __launch_bounds__(256) void qkv_rope_k(const float* __restrict__ x, const float* __restrict__ W,
                                                  const float* __restrict__ bias,
                                                  const float2* __restrict__ tab,
                                                  u16* __restrict__ qb, u16* __restrict__ kb,
                                                  u16* __restrict__ vt) {
    __shared__ u16 smem[2 * 128 * 72];
    u16* As = smem;
    u16* Bs = smem + 128 * 72;
    int tid = threadIdx.x;
    int n0 = blockIdx.x * 128, m0 = blockIdx.y * 128;
    int w = tid >> 6, lane = tid & 63, lr = lane & 15, quad = lane >> 4;
    int wr = w >> 1, wc = w & 1;
    f32x4 acc[4][4] = {};
    for (int kt = 0; kt < C_EMB; kt += 64) {
#pragma unroll
        for (int it = 0; it < 8; ++it) {
            int idx = it * 256 + tid;
            int row = idx >> 4, k4 = (idx & 15) << 2;
            f32x4 a = *(const f32x4*)(x + (size_t)(m0 + row) * C_EMB + kt + k4);
            f32x4 b = *(const f32x4*)(W + (size_t)(n0 + row) * C_EMB + kt + k4);
            *(u16x4*)&As[row * 72 + k4] = pack4(a);
            *(u16x4*)&Bs[row * 72 + k4] = pack4(b);
        }
        __syncthreads();
#pragma unroll
        for (int ks = 0; ks < 64; ks += 32) {
            s16x8 af[4], bf[4];
#pragma unroll
            for (int i = 0; i < 4; ++i)
                af[i] = *(const s16x8*)&As[(wr * 64 + i * 16 + lr) * 72 + ks + quad * 8];
#pragma unroll
            for (int j = 0; j < 4; ++j)
                bf[j] = *(const s16x8*)&Bs[(wc * 64 + j * 16 + lr) * 72 + ks + quad * 8];
#pragma unroll
            for (int i = 0; i < 4; ++i)
#pragma unroll
                for (int j = 0; j < 4; ++j) acc[i][j] = MFMA16(af[i], bf[j], acc[i][j]);
        }
        __syncthreads();
    }
    int sec = n0 >> 10;                       // 0=q 1=k 2=v (blocks never straddle)
    float bv[4];
#pragma unroll
    for (int j = 0; j < 4; ++j) bv[j] = bias[n0 + wc * 64 + j * 16 + lr];

    if (sec == 2) {
        // write C tile (+bias) to LDS as [d][m] (136-padded), then coalesced
        // 16B transposed stores to vt[((b*16+h)*64+d)*2048 + t].
        u16* Ct = smem;                        // 128 x 136 u16 = 34816 <= 36864
#pragma unroll
        for (int i = 0; i < 4; ++i)
#pragma unroll
            for (int j = 0; j < 4; ++j) {
                f32x4 vv;
#pragma unroll
                for (int r = 0; r < 4; ++r) vv[r] = acc[i][j][r] + bv[j];
                int d = wc * 64 + j * 16 + lr;
                int m4 = wr * 64 + i * 16 + quad * 4;
                *(u16x4*)&Ct[d * 136 + m4] = pack4(vv);
            }
        __syncthreads();
        int h0 = (n0 & 1023) >> 6;
        int b = m0 >> 11, tbase = m0 & 2047;
        size_t hb = (size_t)(b * NH);
#pragma unroll
        for (int p = 0; p < 8; ++p) {
            int idx = p * 256 + tid;
            int d = idx >> 4, mc = (idx & 15) << 3;
            s16x8 vdat = *(const s16x8*)&Ct[d * 136 + mc];
            int h = h0 + (d >> 6), dd = d & 63;
            *(s16x8*)(vt + ((hb + h) * HD + dd) * T_SEQ + tbase + mc) = vdat;
        }
    } else {
        u16* dst = (sec == 0) ? qb : kb;
        float qs = (sec == 0) ? 0.125f : 1.0f;   // fold 1/sqrt(D) into q
        int h = ((n0 & 1023) >> 6) + wc;
#pragma unroll
        for (int i = 0; i < 4; ++i)
#pragma unroll
            for (int r = 0; r < 4; ++r) {
                int m = m0 + wr * 64 + i * 16 + quad * 4 + r;
                int b = m >> 11, t = m & 2047;
                size_t base = ((size_t)(b * NH + h) * T_SEQ + t) * HD;
#pragma unroll
                for (int j = 0; j < 2; ++j) {
                    int d1 = j * 16 + lr;                 // 0..31; partner +32 in tile j+2
                    float2 cs = tab[t * 32 + d1];
                    float v1 = acc[i][j][r] + bv[j];
                    float v2 = acc[i][j + 2][r] + bv[j + 2];
                    dst[base + d1]      = f2bf((v1 * cs.x - v2 * cs.y) * qs);
                    dst[base + d1 + 32] = f2bf((v2 * cs.x + v1 * cs.y) * qs);
                }
            }
    }
}

// ---------------- k2: flash attention (MFMA, LDS-staged K/V) ----------------
// grid (16, 32): 128-row Q tile, bh. Wave w owns rows [q0+w*32, +32) = 2 strips.
__global__ __launch_bounds__(256) void flash_k(const u16* __restrict__ qb, const u16* __restrict__ kb,
                                               const u16* __restrict__ vt, u16* __restrict__ yab) {
    __shared__ u16 Ks[64 * 72];
    __shared__ u16 Vs[64 * 72];
    __shared__ u16 Ps[4][32 * 72];
    int tid = threadIdx.x;
    int bx = blockIdx.x, by = blockIdx.y;
    int qt = (by < 16) ? (15 - bx) : bx;      // complementary pairing for balance
    int bh = by;
    int w = tid >> 6, lane = tid & 63, lr = lane & 15, quad = lane >> 4;
    int q0 = qt * 128;
    const u16* qh = qb + (size_t)bh * T_SEQ * HD;
    const u16* kh = kb + (size_t)bh * T_SEQ * HD;
    const u16* vh = vt + (size_t)bh * HD * T_SEQ;

    s16x8 aq[2][2];
#pragma unroll
    for (int s = 0; s < 2; ++s)
#pragma unroll
        for (int ks = 0; ks < 2; ++ks)
            aq[s][ks] = *(const s16x8*)(qh + (size_t)(q0 + w * 32 + s * 16 + lr) * HD + ks * 32 + quad * 8);

    float m_i[2][4], l_i[2][4];
#pragma unroll
    for (int s = 0; s < 2; ++s)
#pragma unroll
        for (int r = 0; r < 4; ++r) { m_i[s][r] = -1e30f; l_i[s][r] = 0.f; }
    f32x4 oacc[2][4] = {};

    int ktmax = 2 * qt + 1;
    for (int kt = 0; kt <= ktmax; ++kt) {
        int k0 = kt * 64;
        // cooperative staging: K[t][d] and V[d][t], 64x72-padded each
#pragma unroll
        for (int p = 0; p < 2; ++p) {
            int idx = p * 256 + tid;
            int row = idx >> 3, c8 = (idx & 7) << 3;
            *(s16x8*)&Ks[row * 72 + c8] = *(const s16x8*)(kh + (size_t)(k0 + row) * HD + c8);
            *(s16x8*)&Vs[row * 72 + c8] = *(const s16x8*)(vh + (size_t)row * T_SEQ + k0 + c8);
        }
        __syncthreads();
        s16x8 bk[2][4];
#pragma unroll
        for (int ks = 0; ks < 2; ++ks)
#pragma unroll
            for (int tc = 0; tc < 4; ++tc)
                bk[ks][tc] = *(const s16x8*)&Ks[(tc * 16 + lr) * 72 + ks * 32 + quad * 8];

#pragma unroll
        for (int s = 0; s < 2; ++s) {
            int rbase = q0 + w * 32 + s * 16;
            if (k0 > rbase + 15) continue;     // strip fully above diagonal
            f32x4 sacc[4] = {};
#pragma unroll
            for (int ks = 0; ks < 2; ++ks)
#pragma unroll
                for (int tc = 0; tc < 4; ++tc) sacc[tc] = MFMA16(aq[s][ks], bk[ks][tc], sacc[tc]);
            if (k0 + 63 > rbase) {
#pragma unroll
                for (int tc = 0; tc < 4; ++tc)
#pragma unroll
                    for (int r = 0; r < 4; ++r)
                        if (k0 + tc * 16 + lr > rbase + quad * 4 + r) sacc[tc][r] = -1e30f;
            }
            float alpha[4];
#pragma unroll
            for (int r = 0; r < 4; ++r) {
                float mx = fmaxf(fmaxf(sacc[0][r], sacc[1][r]), fmaxf(sacc[2][r], sacc[3][r]));
#pragma unroll
                for (int off = 1; off < 16; off <<= 1) mx = fmaxf(mx, __shfl_xor(mx, off, 64));
                float mn = fmaxf(m_i[s][r], mx);
                alpha[r] = __expf(m_i[s][r] - mn);
                m_i[s][r] = mn;
                float rs = 0.f;
#pragma unroll
                for (int tc = 0; tc < 4; ++tc) {
                    float p = __expf(sacc[tc][r] - mn);
                    sacc[tc][r] = p;
                    rs += p;
                }
#pragma unroll
                for (int off = 1; off < 16; off <<= 1) rs += __shfl_xor(rs, off, 64);
                l_i[s][r] = l_i[s][r] * alpha[r] + rs;
            }
            // P (C-layout) -> per-wave LDS -> A-layout; rescale O
#pragma unroll
            for (int tc = 0; tc < 4; ++tc)
#pragma unroll
                for (int r = 0; r < 4; ++r)
                    Ps[w][(s * 16 + quad * 4 + r) * 72 + tc * 16 + lr] = f2bf(sacc[tc][r]);
#pragma unroll
            for (int tn = 0; tn < 4; ++tn)
#pragma unroll
                for (int r = 0; r < 4; ++r) oacc[s][tn][r] *= alpha[r];
#pragma unroll
            for (int ks = 0; ks < 2; ++ks) {
                s16x8 ap = *(const s16x8*)&Ps[w][(s * 16 + lr) * 72 + ks * 32 + quad * 8];
#pragma unroll
                for (int tn = 0; tn < 4; ++tn) {
                    s16x8 bv = *(const s16x8*)&Vs[(tn * 16 + lr) * 72 + ks * 32 + quad * 8];
                    oacc[s][tn] = MFMA16(ap, bv, oacc[s][tn]);
                }
            }
        }
        __syncthreads();                       // protect Ks/Vs for next tile
    }
    int b = bh >> 4, hh = bh & 15;
#pragma unroll
    for (int s = 0; s < 2; ++s)
#pragma unroll
        for (int r = 0; r < 4; ++r) {
            float inv = 1.f / l_i[s][r];
            int t = q0 + w * 32 + s * 16 + quad * 4 + r;
            size_t base = ((size_t)b * T_SEQ + t) * C_EMB + hh * HD;
#pragma unroll
            for (int tn = 0; tn < 4; ++tn)
                yab[base + tn * 16 + lr] = f2bf(oacc[s][tn][r] * inv);
        }
}

// ---------------- k3: output projection (MFMA) ----------------
// grid (8, 32): n0 = bx*128 (0..1023), m0 = by*128
__global__ __launch_bounds__(256) void proj_k(const u16* __restrict__ ya, const float* __restrict__ W,
                                              const float* __restrict__ bias, float* __restrict__ out) {
    __shared__ u16 As[128 * 72];
    __shared__ u16 Bs[128 * 72];
    int tid = threadIdx.x;
    int n0 = blockIdx.x * 128, m0 = blockIdx.y * 128;
    int w = tid >> 6, lane = tid & 63, lr = lane & 15, quad = lane >> 4;
    int wr = w >> 1, wc = w & 1;
    f32x4 acc[4][4] = {};
    for (int kt = 0; kt < C_EMB; kt += 64) {
#pragma unroll
        for (int it = 0; it < 8; ++it) {
            int idx = it * 256 + tid;
            int row = idx >> 4, k4 = (idx & 15) << 2;
            *(u16x4*)&As[row * 72 + k4] = *(const u16x4*)(ya + (size_t)(m0 + row) * C_EMB + kt + k4);
            f32x4 b = *(const f32x4*)(W + (size_t)(n0 + row) * C_EMB + kt + k4);
            *(u16x4*)&Bs[row * 72 + k4] = pack4(b);
        }
        __syncthreads();
#pragma unroll
        for (int ks = 0; ks < 64; ks += 32) {
            s16x8 af[4], bf[4];
#pragma unroll
            for (int i = 0; i < 4; ++i)
                af[i] = *(const s16x8*)&As[(wr * 64 + i * 16 + lr) * 72 + ks + quad * 8];
#pragma unroll
            for (int j = 0; j < 4; ++j)
                bf[j] = *(const s16x8*)&Bs[(wc * 64 + j * 16 + lr) * 72 + ks + quad * 8];
#pragma unroll
            for (int i = 0; i < 4; ++i)
#pragma unroll
                for (int j = 0; j < 4; ++j) acc[i][j] = MFMA16(af[i], bf[j], acc[i][j]);
        }
        __syncthreads();
    }
    float bv[4];
#pragma unroll
    for (int j = 0; j < 4; ++j) bv[j] = bias[n0 + wc * 64 + j * 16 + lr];
#pragma unroll
    for (int i = 0; i < 4; ++i)
#pragma unroll
        for (int r = 0; r < 4; ++r) {
            int m = m0 + wr * 64 + i * 16 + quad * 4 + r;
#pragma unroll
            for (int j = 0; j < 4; ++j)
                out[(size_t)m * C_EMB + n0 + wc * 64 + j * 16 + lr] = acc[i][j][r] + bv[j];
        }
}

extern "C" void kernel_launch(void* const* d_in, const int* in_sizes, int n_in,
                              void* d_out, int out_size, void* d_ws, size_t ws_size,
                              hipStream_t stream) {
    // Inputs resolved BY ELEMENT COUNT (unique): x 4194304, W_attn 3145728,
    // b_attn 3072, W_proj 1048576, b_proj 1024. All fp32.
    const float *x = nullptr, *Wa = nullptr, *ba = nullptr, *Wp = nullptr, *bp = nullptr;
    for (int i = 0; i < n_in; ++i) {
        switch (in_sizes[i]) {
            case 4194304: x  = (const float*)d_in[i]; break;
            case 3145728: Wa = (const float*)d_in[i]; break;
            case 3072:    ba = (const float*)d_in[i]; break;
            case 1048576: Wp = (const float*)d_in[i]; break;
            case 1024:    bp = (const float*)d_in[i]; break;
            default: break;
        }
    }
    float* out = (float*)d_out;

    char* ws = (char*)d_ws;
    u16* qb     = (u16*)(ws);                    //  0.. 8 MiB  bf16 [B,H,T,D] (q*0.125)
    u16* kb     = (u16*)(ws + 8388608);          //  8..16 MiB  bf16 [B,H,T,D]
    u16* vt     = (u16*)(ws + 16777216);         // 16..24 MiB  bf16 [B,H,D,T]
    u16* yab    = (u16*)(ws + 25165824);         // 24..32 MiB  bf16 [B,T,C]
    float2* tab = (float2*)(ws + 33554432);      // 32..32.5 MiB

    rope_tab_k<<<256, 256, 0, stream>>>(tab);
    qkv_rope_k<<<dim3(24, 32), 256, 0, stream>>>(x, Wa, ba, tab, qb, kb, vt);
    flash_k<<<dim3(16, 32), 256, 0, stream>>>(qb, kb, vt, yab);
    proj_k<<<dim3(8, 32), 256, 0, stream>>>(yab, Wp, bp, out);
}

// Round 11
// 251.288 us; speedup vs baseline: 47.1419x; 1.2752x over previous
//
#include <hip/hip_runtime.h>

// B=2, T=2048, C=1024, H=16, D=64. Inputs fp32, OUTPUT fp32.
// Round 11: pre-convert x/W_attn/W_proj to bf16 once; GEMM K-loops stage raw
// bf16 (no per-iter pack VALU, half the fetch bytes). Rest = round 10.
//   k0a: convert fp32->bf16 (x, Wa, Wp);  k0b: rope cos/sin table
//   k1: qkv GEMM 128x128 MFMA + rope epilogue; q(*0.125),k bf16 [B,H,T,D];
//       V transposed to [B,H,D,T] via LDS (coalesced 16B stores).
//   k2: flash: 128-row Q tile, 4 waves x 2 strips; K/V staged in LDS;
//       online softmax via 16-lane shfl; P via per-wave LDS.
//   k3: proj GEMM 128x128 MFMA -> fp32.
// MFMA 16x16x32_bf16 layouts (HW-verified): A: m=lane&15,k=quad*8+j;
// B: k=quad*8+j,n=lane&15; C/D: col=lane&15,row=quad*4+reg.

typedef unsigned short u16;
typedef u16 u16x4 __attribute__((ext_vector_type(4)));
typedef u16 u16x8 __attribute__((ext_vector_type(8)));
typedef short s16x8 __attribute__((ext_vector_type(8)));
typedef float f32x4 __attribute__((ext_vector_type(4)));

#define T_SEQ 2048
#define C_EMB 1024
#define NH 16
#define HD 64

#define MFMA16(a, b, c) __builtin_amdgcn_mfma_f32_16x16x32_bf16(a, b, c, 0, 0, 0)

__device__ __forceinline__ u16 f2bf(float f) {
    union { float f; unsigned int i; } x; x.f = f;
    unsigned int r = x.i + 0x7fffu + ((x.i >> 16) & 1u);
    return (u16)(r >> 16);
}
__device__ __forceinline__ u16x4 pack4(f32x4 v) {
    u16x4 o;
#pragma unroll
    for (int j = 0; j < 4; ++j) o[j] = f2bf(v[j]);
    return o;
}

// ---------------- k0a: fp32 -> bf16 convert ----------------
__global__ __launch_bounds__(256) void conv_k(const float* __restrict__ src, u16* __restrict__ dst, int n8) {
    int i = blockIdx.x * 256 + threadIdx.x;
    if (i >= n8) return;
    f32x4 a = ((const f32x4*)src)[i * 2];
    f32x4 b = ((const f32x4*)src)[i * 2 + 1];
    u16x8 o;
#pragma unroll
    for (int j = 0; j < 4; ++j) o[j] = f2bf(a[j]);
#pragma unroll
    for (int j = 0; j < 4; ++j) o[4 + j] = f2bf(b[j]);
    ((u16x8*)dst)[i] = o;
}

// ---------------- k0b: rope tables ----------------
__global__ __launch_bounds__(256) void rope_tab_k(float2* __restrict__ tab) {
    int idx = blockIdx.x * 256 + threadIdx.x;   // 65536 = T*32
    int t = idx >> 5, j = idx & 31;
    float inv = __builtin_exp2f(-0.41524101186092f * (float)j);  // 10000^(-j/32)
    float s_, c_;
    sincosf((float)t * inv, &s_, &c_);
    tab[idx] = make_float2(c_, s_);
}

// ---------------- k1: QKV GEMM + RoPE (MFMA, bf16 inputs) ----------------
// grid (24, 32): n0 = bx*128 (0..3071), m0 = by*128 (0..4095)
__global__ __launch_bounds__(256) void qkv_rope_k(const u16* __restrict__ xb, const u16* __restrict__ Wab,
                                                  const float* __restrict__ bias,
                                                  const float2* __restrict__ tab,
                                                  u16* __restrict__ qb, u16* __restrict__ kb,
                                                  u16* __restrict__ vt) {
    __shared__ u16 smem[2 * 128 * 72];
    u16* As = smem;
    u16* Bs = smem + 128 * 72;
    int tid = threadIdx.x;
    int n0 = blockIdx.x * 128, m0 = blockIdx.y * 128;
    int w = tid >> 6, lane = tid & 63, lr = lane & 15, quad = lane >> 4;
    int wr = w >> 1, wc = w & 1;
    f32x4 acc[4][4] = {};
    for (int kt = 0; kt < C_EMB; kt += 64) {
#pragma unroll
        for (int it = 0; it < 4; ++it) {
            int idx = it * 256 + tid;
            int row = idx >> 3, c8 = (idx & 7) << 3;
            *(s16x8*)&As[row * 72 + c8] = *(const s16x8*)(xb + (size_t)(m0 + row) * C_EMB + kt + c8);
            *(s16x8*)&Bs[row * 72 + c8] = *(const s16x8*)(Wab + (size_t)(n0 + row) * C_EMB + kt + c8);
        }
        __syncthreads();
#pragma unroll
        for (int ks = 0; ks < 64; ks += 32) {
            s16x8 af[4], bf[4];
#pragma unroll
            for (int i = 0; i < 4; ++i)
                af[i] = *(const s16x8*)&As[(wr * 64 + i * 16 + lr) * 72 + ks + quad * 8];
#pragma unroll
            for (int j = 0; j < 4; ++j)
                bf[j] = *(const s16x8*)&Bs[(wc * 64 + j * 16 + lr) * 72 + ks + quad * 8];
#pragma unroll
            for (int i = 0; i < 4; ++i)
#pragma unroll
                for (int j = 0; j < 4; ++j) acc[i][j] = MFMA16(af[i], bf[j], acc[i][j]);
        }
        __syncthreads();
    }
    int sec = n0 >> 10;                       // 0=q 1=k 2=v (blocks never straddle)
    float bv[4];
#pragma unroll
    for (int j = 0; j < 4; ++j) bv[j] = bias[n0 + wc * 64 + j * 16 + lr];

    if (sec == 2) {
        // C tile (+bias) -> LDS [d][m] (136-padded) -> coalesced 16B
        // transposed stores to vt[((b*16+h)*64+d)*2048 + t].
        u16* Ct = smem;                        // 128 x 136 u16 = 34816 <= 36864
#pragma unroll
        for (int i = 0; i < 4; ++i)
#pragma unroll
            for (int j = 0; j < 4; ++j) {
                f32x4 vv;
#pragma unroll
                for (int r = 0; r < 4; ++r) vv[r] = acc[i][j][r] + bv[j];
                int d = wc * 64 + j * 16 + lr;
                int m4 = wr * 64 + i * 16 + quad * 4;
                *(u16x4*)&Ct[d * 136 + m4] = pack4(vv);
            }
        __syncthreads();
        int h0 = (n0 & 1023) >> 6;
        int b = m0 >> 11, tbase = m0 & 2047;
        size_t hb = (size_t)(b * NH);
#pragma unroll
        for (int p = 0; p < 8; ++p) {
            int idx = p * 256 + tid;
            int d = idx >> 4, mc = (idx & 15) << 3;
            s16x8 vdat = *(const s16x8*)&Ct[d * 136 + mc];
            int h = h0 + (d >> 6), dd = d & 63;
            *(s16x8*)(vt + ((hb + h) * HD + dd) * T_SEQ + tbase + mc) = vdat;
        }
    } else {
        u16* dst = (sec == 0) ? qb : kb;
        float qs = (sec == 0) ? 0.125f : 1.0f;   // fold 1/sqrt(D) into q
        int h = ((n0 & 1023) >> 6) + wc;
#pragma unroll
        for (int i = 0; i < 4; ++i)
#pragma unroll
            for (int r = 0; r < 4; ++r) {
                int m = m0 + wr * 64 + i * 16 + quad * 4 + r;
                int b = m >> 11, t = m & 2047;
                size_t base = ((size_t)(b * NH + h) * T_SEQ + t) * HD;
#pragma unroll
                for (int j = 0; j < 2; ++j) {
                    int d1 = j * 16 + lr;                 // 0..31; partner +32 in tile j+2
                    float2 cs = tab[t * 32 + d1];
                    float v1 = acc[i][j][r] + bv[j];
                    float v2 = acc[i][j + 2][r] + bv[j + 2];
                    dst[base + d1]      = f2bf((v1 * cs.x - v2 * cs.y) * qs);
                    dst[base + d1 + 32] = f2bf((v2 * cs.x + v1 * cs.y) * qs);
                }
            }
    }
}

// ---------------- k2: flash attention (MFMA, LDS-staged K/V) ----------------
// grid (16, 32): 128-row Q tile, bh. Wave w owns rows [q0+w*32, +32) = 2 strips.
__global__ __launch_bounds__(256) void flash_k(const u16* __restrict__ qb, const u16* __restrict__ kb,
                                               const u16* __restrict__ vt, u16* __restrict__ yab) {
    __shared__ u16 Ks[64 * 72];
    __shared__ u16 Vs[64 * 72];
    __shared__ u16 Ps[4][32 * 72];
    int tid = threadIdx.x;
    int bx = blockIdx.x, by = blockIdx.y;
    int qt = (by < 16) ? (15 - bx) : bx;      // complementary pairing for balance
    int bh = by;
    int w = tid >> 6, lane = tid & 63, lr = lane & 15, quad = lane >> 4;
    int q0 = qt * 128;
    const u16* qh = qb + (size_t)bh * T_SEQ * HD;
    const u16* kh = kb + (size_t)bh * T_SEQ * HD;
    const u16* vh = vt + (size_t)bh * HD * T_SEQ;

    s16x8 aq[2][2];
#pragma unroll
    for (int s = 0; s < 2; ++s)
#pragma unroll
        for (int ks = 0; ks < 2; ++ks)
            aq[s][ks] = *(const s16x8*)(qh + (size_t)(q0 + w * 32 + s * 16 + lr) * HD + ks * 32 + quad * 8);

    float m_i[2][4], l_i[2][4];
#pragma unroll
    for (int s = 0; s < 2; ++s)
#pragma unroll
        for (int r = 0; r < 4; ++r) { m_i[s][r] = -1e30f; l_i[s][r] = 0.f; }
    f32x4 oacc[2][4] = {};

    int ktmax = 2 * qt + 1;
    for (int kt = 0; kt <= ktmax; ++kt) {
        int k0 = kt * 64;
        // cooperative staging: K[t][d] and V[d][t], 64x72-padded each
#pragma unroll
        for (int p = 0; p < 2; ++p) {
            int idx = p * 256 + tid;
            int row = idx >> 3, c8 = (idx & 7) << 3;
            *(s16x8*)&Ks[row * 72 + c8] = *(const s16x8*)(kh + (size_t)(k0 + row) * HD + c8);
            *(s16x8*)&Vs[row * 72 + c8] = *(const s16x8*)(vh + (size_t)row * T_SEQ + k0 + c8);
        }
        __syncthreads();
        s16x8 bk[2][4];
#pragma unroll
        for (int ks = 0; ks < 2; ++ks)
#pragma unroll
            for (int tc = 0; tc < 4; ++tc)
                bk[ks][tc] = *(const s16x8*)&Ks[(tc * 16 + lr) * 72 + ks * 32 + quad * 8];

#pragma unroll
        for (int s = 0; s < 2; ++s) {
            int rbase = q0 + w * 32 + s * 16;
            if (k0 > rbase + 15) continue;     // strip fully above diagonal
            f32x4 sacc[4] = {};
#pragma unroll
            for (int ks = 0; ks < 2; ++ks)
#pragma unroll
                for (int tc = 0; tc < 4; ++tc) sacc[tc] = MFMA16(aq[s][ks], bk[ks][tc], sacc[tc]);
            if (k0 + 63 > rbase) {
#pragma unroll
                for (int tc = 0; tc < 4; ++tc)
#pragma unroll
                    for (int r = 0; r < 4; ++r)
                        if (k0 + tc * 16 + lr > rbase + quad * 4 + r) sacc[tc][r] = -1e30f;
            }
            float alpha[4];
#pragma unroll
            for (int r = 0; r < 4; ++r) {
                float mx = fmaxf(fmaxf(sacc[0][r], sacc[1][r]), fmaxf(sacc[2][r], sacc[3][r]));
#pragma unroll
                for (int off = 1; off < 16; off <<= 1) mx = fmaxf(mx, __shfl_xor(mx, off, 64));
                float mn = fmaxf(m_i[s][r], mx);
                alpha[r] = __expf(m_i[s][r] - mn);
                m_i[s][r] = mn;
                float rs = 0.f;
#pragma unroll
                for (int tc = 0; tc < 4; ++tc) {
                    float p = __expf(sacc[tc][r] - mn);
                    sacc[tc][r] = p;
                    rs += p;
                }
#pragma unroll
                for (int off = 1; off < 16; off <<= 1) rs += __shfl_xor(rs, off, 64);
                l_i[s][r] = l_i[s][r] * alpha[r] + rs;
            }
            // P (C-layout) -> per-wave LDS -> A-layout; rescale O
#pragma unroll
            for (int tc = 0; tc < 4; ++tc)
#pragma unroll
                for (int r = 0; r < 4; ++r)
                    Ps[w][(s * 16 + quad * 4 + r) * 72 + tc * 16 + lr] = f2bf(sacc[tc][r]);
#pragma unroll
            for (int tn = 0; tn < 4; ++tn)
#pragma unroll
                for (int r = 0; r < 4; ++r) oacc[s][tn][r] *= alpha[r];
#pragma unroll
            for (int ks = 0; ks < 2; ++ks) {
                s16x8 ap = *(const s16x8*)&Ps[w][(s * 16 + lr) * 72 + ks * 32 + quad * 8];
#pragma unroll
                for (int tn = 0; tn < 4; ++tn) {
                    s16x8 bv = *(const s16x8*)&Vs[(tn * 16 + lr) * 72 + ks * 32 + quad * 8];
                    oacc[s][tn] = MFMA16(ap, bv, oacc[s][tn]);
                }
            }
        }
        __syncthreads();                       // protect Ks/Vs for next tile
    }
    int b = bh >> 4, hh = bh & 15;
#pragma unroll
    for (int s = 0; s < 2; ++s)
#pragma unroll
        for (int r = 0; r < 4; ++r) {
            float inv = 1.f / l_i[s][r];
            int t = q0 + w * 32 + s * 16 + quad * 4 + r;
            size_t base = ((size_t)b * T_SEQ + t) * C_EMB + hh * HD;
#pragma unroll
            for (int tn = 0; tn < 4; ++tn)
                yab[base + tn * 16 + lr] = f2bf(oacc[s][tn][r] * inv);
        }
}

// ---------------- k3: output projection (MFMA, bf16 inputs) ----------------
// grid (8, 32): n0 = bx*128 (0..1023), m0 = by*128
__global__ __launch_bounds__(256) void proj_k(const u16* __restrict__ ya, const u16* __restrict__ Wpb,
                                              const float* __restrict__ bias, float* __restrict__ out) {
    __shared__ u16 As[128 * 72];
    __shared__ u16 Bs[128 * 72];
    int tid = threadIdx.x;
    int n0 = blockIdx.x * 128, m0 = blockIdx.y * 128;
    int w = tid >> 6, lane = tid & 63, lr = lane & 15, quad = lane >> 4;
    int wr = w >> 1, wc = w & 1;
    f32x4 acc[4][4] = {};
    for (int kt = 0; kt < C_EMB; kt += 64) {
#pragma unroll
        for (int it = 0; it < 4; ++it) {
            int idx = it * 256 + tid;
            int row = idx >> 3, c8 = (idx & 7) << 3;
            *(s16x8*)&As[row * 72 + c8] = *(const s16x8*)(ya + (size_t)(m0 + row) * C_EMB + kt + c8);
            *(s16x8*)&Bs[row * 72 + c8] = *(const s16x8*)(Wpb + (size_t)(n0 + row) * C_EMB + kt + c8);
        }
        __syncthreads();
#pragma unroll
        for (int ks = 0; ks < 64; ks += 32) {
            s16x8 af[4], bf[4];
#pragma unroll
            for (int i = 0; i < 4; ++i)
                af[i] = *(const s16x8*)&As[(wr * 64 + i * 16 + lr) * 72 + ks + quad * 8];
#pragma unroll
            for (int j = 0; j < 4; ++j)
                bf[j] = *(const s16x8*)&Bs[(wc * 64 + j * 16 + lr) * 72 + ks + quad * 8];
#pragma unroll
            for (int i = 0; i < 4; ++i)
#pragma unroll
                for (int j = 0; j < 4; ++j) acc[i][j] = MFMA16(af[i], bf[j], acc[i][j]);
        }
        __syncthreads();
    }
    float bv[4];
#pragma unroll
    for (int j = 0; j < 4; ++j) bv[j] = bias[n0 + wc * 64 + j * 16 + lr];
#pragma unroll
    for (int i = 0; i < 4; ++i)
#pragma unroll
        for (int r = 0; r < 4; ++r) {
            int m = m0 + wr * 64 + i * 16 + quad * 4 + r;
#pragma unroll
            for (int j = 0; j < 4; ++j)
                out[(size_t)m * C_EMB + n0 + wc * 64 + j * 16 + lr] = acc[i][j][r] + bv[j];
        }
}

extern "C" void kernel_launch(void* const* d_in, const int* in_sizes, int n_in,
                              void* d_out, int out_size, void* d_ws, size_t ws_size,
                              hipStream_t stream) {
    // Inputs resolved BY ELEMENT COUNT (unique): x 4194304, W_attn 3145728,
    // b_attn 3072, W_proj 1048576, b_proj 1024. All fp32.
    const float *x = nullptr, *Wa = nullptr, *ba = nullptr, *Wp = nullptr, *bp = nullptr;
    for (int i = 0; i < n_in; ++i) {
        switch (in_sizes[i]) {
            case 4194304: x  = (const float*)d_in[i]; break;
            case 3145728: Wa = (const float*)d_in[i]; break;
            case 3072:    ba = (const float*)d_in[i]; break;
            case 1048576: Wp = (const float*)d_in[i]; break;
            case 1024:    bp = (const float*)d_in[i]; break;
            default: break;
        }
    }
    float* out = (float*)d_out;

    char* ws = (char*)d_ws;
    u16* qb     = (u16*)(ws);                    //  0.. 8 MiB  bf16 [B,H,T,D] (q*0.125)
    u16* kb     = (u16*)(ws + 8388608);          //  8..16 MiB  bf16 [B,H,T,D]
    u16* vt     = (u16*)(ws + 16777216);         // 16..24 MiB  bf16 [B,H,D,T]
    u16* yab    = (u16*)(ws + 25165824);         // 24..32 MiB  bf16 [B,T,C]
    float2* tab = (float2*)(ws + 33554432);      // 32..32.5 MiB
    u16* xb     = (u16*)(ws + 35651584);         // 34..42 MiB  bf16 [4096,1024]
    u16* Wab    = (u16*)(ws + 44040192);         // 42..48 MiB  bf16 [3072,1024]
    u16* Wpb    = (u16*)(ws + 50331648);         // 48..50 MiB  bf16 [1024,1024]

    conv_k<<<2048, 256, 0, stream>>>(x, xb, 524288);
    conv_k<<<1536, 256, 0, stream>>>(Wa, Wab, 393216);
    conv_k<<<512, 256, 0, stream>>>(Wp, Wpb, 131072);
    rope_tab_k<<<256, 256, 0, stream>>>(tab);
    qkv_rope_k<<<dim3(24, 32), 256, 0, stream>>>(xb, Wab, ba, tab, qb, kb, vt);
    flash_k<<<dim3(16, 32), 256, 0, stream>>>(qb, kb, vt, yab);
    proj_k<<<dim3(8, 32), 256, 0, stream>>>(yab, Wpb, bp, out);
}

// Round 12
// 222.092 us; speedup vs baseline: 53.3392x; 1.1315x over previous
//
#include <hip/hip_runtime.h>

// B=2, T=2048, C=1024, H=16, D=64. Inputs fp32, OUTPUT fp32.
// Round 12: flash computes S^T / O^T (MFMA operand swap) -> per-lane softmax
// (in-lane reductions + 2 shfls instead of 16), u16x4 P/ya writes; qkv q/k
// epilogue through LDS transpose (coalesced b128 stores). Rest = round 11.
// MFMA 16x16x32_bf16 layouts (HW-verified): A: m=lane&15,k=quad*8+j;
// B: k=quad*8+j,n=lane&15; C/D: col=lane&15,row=quad*4+reg.

typedef unsigned short u16;
typedef u16 u16x4 __attribute__((ext_vector_type(4)));
typedef u16 u16x8 __attribute__((ext_vector_type(8)));
typedef short s16x8 __attribute__((ext_vector_type(8)));
typedef float f32x4 __attribute__((ext_vector_type(4)));

#define T_SEQ 2048
#define C_EMB 1024
#define NH 16
#define HD 64

#define MFMA16(a, b, c) __builtin_amdgcn_mfma_f32_16x16x32_bf16(a, b, c, 0, 0, 0)

__device__ __forceinline__ u16 f2bf(float f) {
    union { float f; unsigned int i; } x; x.f = f;
    unsigned int r = x.i + 0x7fffu + ((x.i >> 16) & 1u);
    return (u16)(r >> 16);
}
__device__ __forceinline__ u16x4 pack4(f32x4 v) {
    u16x4 o;
#pragma unroll
    for (int j = 0; j < 4; ++j) o[j] = f2bf(v[j]);
    return o;
}

// ---------------- k0a: fp32 -> bf16 convert ----------------
__global__ __launch_bounds__(256) void conv_k(const float* __restrict__ src, u16* __restrict__ dst, int n8) {
    int i = blockIdx.x * 256 + threadIdx.x;
    if (i >= n8) return;
    f32x4 a = ((const f32x4*)src)[i * 2];
    f32x4 b = ((const f32x4*)src)[i * 2 + 1];
    u16x8 o;
#pragma unroll
    for (int j = 0; j < 4; ++j) o[j] = f2bf(a[j]);
#pragma unroll
    for (int j = 0; j < 4; ++j) o[4 + j] = f2bf(b[j]);
    ((u16x8*)dst)[i] = o;
}

// ---------------- k0b: rope tables ----------------
__global__ __launch_bounds__(256) void rope_tab_k(float2* __restrict__ tab) {
    int idx = blockIdx.x * 256 + threadIdx.x;   // 65536 = T*32
    int t = idx >> 5, j = idx & 31;
    float inv = __builtin_exp2f(-0.41524101186092f * (float)j);  // 10000^(-j/32)
    float s_, c_;
    sincosf((float)t * inv, &s_, &c_);
    tab[idx] = make_float2(c_, s_);
}

// ---------------- k1: QKV GEMM + RoPE (MFMA, bf16 inputs) ----------------
// grid (24, 32): n0 = bx*128 (0..3071), m0 = by*128 (0..4095)
__global__ __launch_bounds__(256) void qkv_rope_k(const u16* __restrict__ xb, const u16* __restrict__ Wab,
                                                  const float* __restrict__ bias,
                                                  const float2* __restrict__ tab,
                                                  u16* __restrict__ qb, u16* __restrict__ kb,
                                                  u16* __restrict__ vt) {
    __shared__ u16 smem[2 * 128 * 72];
    u16* As = smem;
    u16* Bs = smem + 128 * 72;
    int tid = threadIdx.x;
    int n0 = blockIdx.x * 128, m0 = blockIdx.y * 128;
    int w = tid >> 6, lane = tid & 63, lr = lane & 15, quad = lane >> 4;
    int wr = w >> 1, wc = w & 1;
    f32x4 acc[4][4] = {};
    for (int kt = 0; kt < C_EMB; kt += 64) {
#pragma unroll
        for (int it = 0; it < 4; ++it) {
            int idx = it * 256 + tid;
            int row = idx >> 3, c8 = (idx & 7) << 3;
            *(s16x8*)&As[row * 72 + c8] = *(const s16x8*)(xb + (size_t)(m0 + row) * C_EMB + kt + c8);
            *(s16x8*)&Bs[row * 72 + c8] = *(const s16x8*)(Wab + (size_t)(n0 + row) * C_EMB + kt + c8);
        }
        __syncthreads();
#pragma unroll
        for (int ks = 0; ks < 64; ks += 32) {
            s16x8 af[4], bf[4];
#pragma unroll
            for (int i = 0; i < 4; ++i)
                af[i] = *(const s16x8*)&As[(wr * 64 + i * 16 + lr) * 72 + ks + quad * 8];
#pragma unroll
            for (int j = 0; j < 4; ++j)
                bf[j] = *(const s16x8*)&Bs[(wc * 64 + j * 16 + lr) * 72 + ks + quad * 8];
#pragma unroll
            for (int i = 0; i < 4; ++i)
#pragma unroll
                for (int j = 0; j < 4; ++j) acc[i][j] = MFMA16(af[i], bf[j], acc[i][j]);
        }
        __syncthreads();
    }
    int sec = n0 >> 10;                       // 0=q 1=k 2=v (blocks never straddle)
    float bv[4];
#pragma unroll
    for (int j = 0; j < 4; ++j) bv[j] = bias[n0 + wc * 64 + j * 16 + lr];

    int h0 = (n0 & 1023) >> 6;
    int b = m0 >> 11, tbase = m0 & 2047;
    if (sec == 2) {
        // C tile (+bias) -> LDS [d][m] (136-padded) -> coalesced 16B
        // transposed stores to vt[((b*16+h)*64+d)*2048 + t].
        u16* Ct = smem;                        // 128 x 136 u16 = 34816 B
#pragma unroll
        for (int i = 0; i < 4; ++i)
#pragma unroll
            for (int j = 0; j < 4; ++j) {
                f32x4 vv;
#pragma unroll
                for (int r = 0; r < 4; ++r) vv[r] = acc[i][j][r] + bv[j];
                int d = wc * 64 + j * 16 + lr;
                int m4 = wr * 64 + i * 16 + quad * 4;
                *(u16x4*)&Ct[d * 136 + m4] = pack4(vv);
            }
        __syncthreads();
        size_t hb = (size_t)(b * NH);
#pragma unroll
        for (int p = 0; p < 8; ++p) {
            int idx = p * 256 + tid;
            int d = idx >> 4, mc = (idx & 15) << 3;
            s16x8 vdat = *(const s16x8*)&Ct[d * 136 + mc];
            int h = h0 + (d >> 6), dd = d & 63;
            *(s16x8*)(vt + ((hb + h) * HD + dd) * T_SEQ + tbase + mc) = vdat;
        }
    } else {
        // q/k: RoPE in-register, stage [m][n] in LDS, coalesced b128 stores.
        u16* dst = (sec == 0) ? qb : kb;
        float qs = (sec == 0) ? 0.125f : 1.0f;   // fold 1/sqrt(D) into q
        u16* Ct = smem;                        // 128 x 136 u16
#pragma unroll
        for (int i = 0; i < 4; ++i)
#pragma unroll
            for (int r = 0; r < 4; ++r) {
                int mrow = wr * 64 + i * 16 + quad * 4 + r;
                int t = (m0 + mrow) & 2047;
#pragma unroll
                for (int j = 0; j < 2; ++j) {
                    int d1 = j * 16 + lr;                 // 0..31; partner +32 in tile j+2
                    float2 cs = tab[t * 32 + d1];
                    float v1 = acc[i][j][r] + bv[j];
                    float v2 = acc[i][j + 2][r] + bv[j + 2];
                    int n1 = wc * 64 + j * 16 + lr;
                    Ct[mrow * 136 + n1]      = f2bf((v1 * cs.x - v2 * cs.y) * qs);
                    Ct[mrow * 136 + n1 + 32] = f2bf((v2 * cs.x + v1 * cs.y) * qs);
                }
            }
        __syncthreads();
#pragma unroll
        for (int p = 0; p < 8; ++p) {
            int idx = p * 256 + tid;              // 128 rows x 16 chunks of 8 u16
            int mrow = idx >> 4, c = idx & 15;
            s16x8 vdat = *(const s16x8*)&Ct[mrow * 136 + c * 8];
            int h = h0 + (c >> 3), dd = (c & 7) << 3;
            *(s16x8*)(dst + ((size_t)(b * NH + h) * T_SEQ + tbase + mrow) * HD + dd) = vdat;
        }
    }
}

// ---------------- k2: flash attention (MFMA, S^T/O^T form) ----------------
// grid (16, 32): 128-row Q tile, bh. Wave w owns rows [q0+w*32, +32) = 2 strips.
// S^T tile: elem (k' = k0+tc*16+quad*4+r, q = rbase+lr) — lane owns q-row lr.
__global__ __launch_bounds__(256) void flash_k(const u16* __restrict__ qb, const u16* __restrict__ kb,
                                               const u16* __restrict__ vt, u16* __restrict__ yab) {
    __shared__ u16 Ks[64 * 72];
    __shared__ u16 Vs[64 * 72];
    __shared__ u16 Ps[4][32 * 72];           // [wave][q-row 32][k' 64 pad 72]
    int tid = threadIdx.x;
    int bx = blockIdx.x, by = blockIdx.y;
    int qt = (by < 16) ? (15 - bx) : bx;      // complementary pairing for balance
    int bh = by;
    int w = tid >> 6, lane = tid & 63, lr = lane & 15, quad = lane >> 4;
    int q0 = qt * 128;
    const u16* qh = qb + (size_t)bh * T_SEQ * HD;
    const u16* kh = kb + (size_t)bh * T_SEQ * HD;
    const u16* vh = vt + (size_t)bh * HD * T_SEQ;

    s16x8 aq[2][2];                           // B-frag of Q (n=q-row=lr, k=d)
#pragma unroll
    for (int s = 0; s < 2; ++s)
#pragma unroll
        for (int ks = 0; ks < 2; ++ks)
            aq[s][ks] = *(const s16x8*)(qh + (size_t)(q0 + w * 32 + s * 16 + lr) * HD + ks * 32 + quad * 8);

    float m_i[2] = {-1e30f, -1e30f}, l_i[2] = {0.f, 0.f};
    f32x4 oacc[2][4] = {};                    // O^T: elem (d=tn*16+quad*4+r, q=lr)

    int ktmax = 2 * qt + 1;
    for (int kt = 0; kt <= ktmax; ++kt) {
        int k0 = kt * 64;
        // cooperative staging: K[t][d] and V[d][t], 64x72-padded each
#pragma unroll
        for (int p = 0; p < 2; ++p) {
            int idx = p * 256 + tid;
            int row = idx >> 3, c8 = (idx & 7) << 3;
            *(s16x8*)&Ks[row * 72 + c8] = *(const s16x8*)(kh + (size_t)(k0 + row) * HD + c8);
            *(s16x8*)&Vs[row * 72 + c8] = *(const s16x8*)(vh + (size_t)row * T_SEQ + k0 + c8);
        }
        __syncthreads();
        s16x8 ak[2][4];                       // A-frag of K (m=k-row=lr, k=d)
#pragma unroll
        for (int ks = 0; ks < 2; ++ks)
#pragma unroll
            for (int tc = 0; tc < 4; ++tc)
                ak[ks][tc] = *(const s16x8*)&Ks[(tc * 16 + lr) * 72 + ks * 32 + quad * 8];

#pragma unroll
        for (int s = 0; s < 2; ++s) {
            int rbase = q0 + w * 32 + s * 16;
            if (k0 > rbase + 15) continue;     // strip fully above diagonal
            f32x4 sacc[4] = {};
#pragma unroll
            for (int ks = 0; ks < 2; ++ks)
#pragma unroll
                for (int tc = 0; tc < 4; ++tc) sacc[tc] = MFMA16(ak[ks][tc], aq[s][ks], sacc[tc]);
            if (k0 + 63 > rbase) {
#pragma unroll
                for (int tc = 0; tc < 4; ++tc)
#pragma unroll
                    for (int r = 0; r < 4; ++r)
                        if (k0 + tc * 16 + quad * 4 + r > rbase + lr) sacc[tc][r] = -1e30f;
            }
            // per-lane softmax for q-row (rbase+lr)
            float mx = sacc[0][0];
#pragma unroll
            for (int tc = 0; tc < 4; ++tc)
#pragma unroll
                for (int r = 0; r < 4; ++r) mx = fmaxf(mx, sacc[tc][r]);
            mx = fmaxf(mx, __shfl_xor(mx, 16, 64));
            mx = fmaxf(mx, __shfl_xor(mx, 32, 64));
            float mn = fmaxf(m_i[s], mx);
            float alpha = __expf(m_i[s] - mn);
            m_i[s] = mn;
            float rs = 0.f;
#pragma unroll
            for (int tc = 0; tc < 4; ++tc)
#pragma unroll
                for (int r = 0; r < 4; ++r) {
                    float p = __expf(sacc[tc][r] - mn);
                    sacc[tc][r] = p;
                    rs += p;
                }
            rs += __shfl_xor(rs, 16, 64);
            rs += __shfl_xor(rs, 32, 64);
            l_i[s] = l_i[s] * alpha + rs;
            // P^T -> LDS [q][k'] (u16x4 writes), O rescale by per-lane alpha
#pragma unroll
            for (int tc = 0; tc < 4; ++tc)
                *(u16x4*)&Ps[w][(s * 16 + lr) * 72 + tc * 16 + quad * 4] = pack4(sacc[tc]);
#pragma unroll
            for (int tn = 0; tn < 4; ++tn)
#pragma unroll
                for (int r = 0; r < 4; ++r) oacc[s][tn][r] *= alpha;
#pragma unroll
            for (int ks = 0; ks < 2; ++ks) {
                s16x8 ap = *(const s16x8*)&Ps[w][(s * 16 + lr) * 72 + ks * 32 + quad * 8];
#pragma unroll
                for (int tn = 0; tn < 4; ++tn) {
                    s16x8 av = *(const s16x8*)&Vs[(tn * 16 + lr) * 72 + ks * 32 + quad * 8];
                    oacc[s][tn] = MFMA16(av, ap, oacc[s][tn]);
                }
            }
        }
        __syncthreads();                       // protect Ks/Vs for next tile
    }
    int b = bh >> 4, hh = bh & 15;
#pragma unroll
    for (int s = 0; s < 2; ++s) {
        float inv = 1.f / l_i[s];
        int t = q0 + w * 32 + s * 16 + lr;
        size_t base = ((size_t)b * T_SEQ + t) * C_EMB + hh * HD;
#pragma unroll
        for (int tn = 0; tn < 4; ++tn) {
            f32x4 vv;
#pragma unroll
            for (int r = 0; r < 4; ++r) vv[r] = oacc[s][tn][r] * inv;
            *(u16x4*)(yab + base + tn * 16 + quad * 4) = pack4(vv);
        }
    }
}

// ---------------- k3: output projection (MFMA, bf16 inputs) ----------------
// grid (8, 32): n0 = bx*128 (0..1023), m0 = by*128
__global__ __launch_bounds__(256) void proj_k(const u16* __restrict__ ya, const u16* __restrict__ Wpb,
                                              const float* __restrict__ bias, float* __restrict__ out) {
    __shared__ u16 As[128 * 72];
    __shared__ u16 Bs[128 * 72];
    int tid = threadIdx.x;
    int n0 = blockIdx.x * 128, m0 = blockIdx.y * 128;
    int w = tid >> 6, lane = tid & 63, lr = lane & 15, quad = lane >> 4;
    int wr = w >> 1, wc = w & 1;
    f32x4 acc[4][4] = {};
    for (int kt = 0; kt < C_EMB; kt += 64) {
#pragma unroll
        for (int it = 0; it < 4; ++it) {
            int idx = it * 256 + tid;
            int row = idx >> 3, c8 = (idx & 7) << 3;
            *(s16x8*)&As[row * 72 + c8] = *(const s16x8*)(ya + (size_t)(m0 + row) * C_EMB + kt + c8);
            *(s16x8*)&Bs[row * 72 + c8] = *(const s16x8*)(Wpb + (size_t)(n0 + row) * C_EMB + kt + c8);
        }
        __syncthreads();
#pragma unroll
        for (int ks = 0; ks < 64; ks += 32) {
            s16x8 af[4], bf[4];
#pragma unroll
            for (int i = 0; i < 4; ++i)
                af[i] = *(const s16x8*)&As[(wr * 64 + i * 16 + lr) * 72 + ks + quad * 8];
#pragma unroll
            for (int j = 0; j < 4; ++j)
                bf[j] = *(const s16x8*)&Bs[(wc * 64 + j * 16 + lr) * 72 + ks + quad * 8];
#pragma unroll
            for (int i = 0; i < 4; ++i)
#pragma unroll
                for (int j = 0; j < 4; ++j) acc[i][j] = MFMA16(af[i], bf[j], acc[i][j]);
        }
        __syncthreads();
    }
    float bv[4];
#pragma unroll
    for (int j = 0; j < 4; ++j) bv[j] = bias[n0 + wc * 64 + j * 16 + lr];
#pragma unroll
    for (int i = 0; i < 4; ++i)
#pragma unroll
        for (int r = 0; r < 4; ++r) {
            int m = m0 + wr * 64 + i * 16 + quad * 4 + r;
#pragma unroll
            for (int j = 0; j < 4; ++j)
                out[(size_t)m * C_EMB + n0 + wc * 64 + j * 16 + lr] = acc[i][j][r] + bv[j];
        }
}

extern "C" void kernel_launch(void* const* d_in, const int* in_sizes, int n_in,
                              void* d_out, int out_size, void* d_ws, size_t ws_size,
                              hipStream_t stream) {
    // Inputs resolved BY ELEMENT COUNT (unique): x 4194304, W_attn 3145728,
    // b_attn 3072, W_proj 1048576, b_proj 1024. All fp32.
    const float *x = nullptr, *Wa = nullptr, *ba = nullptr, *Wp = nullptr, *bp = nullptr;
    for (int i = 0; i < n_in; ++i) {
        switch (in_sizes[i]) {
            case 4194304: x  = (const float*)d_in[i]; break;
            case 3145728: Wa = (const float*)d_in[i]; break;
            case 3072:    ba = (const float*)d_in[i]; break;
            case 1048576: Wp = (const float*)d_in[i]; break;
            case 1024:    bp = (const float*)d_in[i]; break;
            default: break;
        }
    }
    float* out = (float*)d_out;

    char* ws = (char*)d_ws;
    u16* qb     = (u16*)(ws);                    //  0.. 8 MiB  bf16 [B,H,T,D] (q*0.125)
    u16* kb     = (u16*)(ws + 8388608);          //  8..16 MiB  bf16 [B,H,T,D]
    u16* vt     = (u16*)(ws + 16777216);         // 16..24 MiB  bf16 [B,H,D,T]
    u16* yab    = (u16*)(ws + 25165824);         // 24..32 MiB  bf16 [B,T,C]
    float2* tab = (float2*)(ws + 33554432);      // 32..32.5 MiB
    u16* xb     = (u16*)(ws + 35651584);         // 34..42 MiB  bf16 [4096,1024]
    u16* Wab    = (u16*)(ws + 44040192);         // 42..48 MiB  bf16 [3072,1024]
    u16* Wpb    = (u16*)(ws + 50331648);         // 48..50 MiB  bf16 [1024,1024]

    conv_k<<<2048, 256, 0, stream>>>(x, xb, 524288);
    conv_k<<<1536, 256, 0, stream>>>(Wa, Wab, 393216);
    conv_k<<<512, 256, 0, stream>>>(Wp, Wpb, 131072);
    rope_tab_k<<<256, 256, 0, stream>>>(tab);
    qkv_rope_k<<<dim3(24, 32), 256, 0, stream>>>(xb, Wab, ba, tab, qb, kb, vt);
    flash_k<<<dim3(16, 32), 256, 0, stream>>>(qb, kb, vt, yab);
    proj_k<<<dim3(8, 32), 256, 0, stream>>>(yab, Wpb, bp, out);
}